// Round 6
// baseline (139.786 us; speedup 1.0000x reference)
//
#include <hip/hip_runtime.h>

#define Bq 64
#define Sq 512
#define Hq 768
#define Tq 16
#define Vq 30522
#define WLP 20    // W LDS row stride in k_table

typedef unsigned int u32;
typedef unsigned long long u64;

// ---------- cross-lane helpers ----------
__device__ __forceinline__ float bperm_f(float v, int byteidx) {
    return __int_as_float(__builtin_amdgcn_ds_bpermute(byteidx, __float_as_int(v)));
}
template <int CTRL>
__device__ __forceinline__ int dpp_i(int v) {
    return __builtin_amdgcn_mov_dpp(v, CTRL, 0xF, 0xF, true);
}
template <int CTRL>
__device__ __forceinline__ float dpp_f(float v) {
    return __int_as_float(dpp_i<CTRL>(__float_as_int(v)));
}

#define QX1 0xB1   // quad_perm [1,0,3,2]
#define QX2 0x4E   // quad_perm [2,3,0,1]
#define QX3 0x1B   // quad_perm [3,2,1,0]
#define RR4  0x124 // row_ror:4
#define RR8  0x128 // row_ror:8
#define RR12 0x12C // row_ror:12

__device__ __forceinline__ u32 packnib(u32 d) {
    u32 y = d | (d >> 4);
    y &= 0x00FF00FFu;
    y = (y | (y >> 8)) & 0xFFFFu;
    return y;
}
__device__ __forceinline__ u32 nib64(u64 f, u32 s) {
    return ((u32)(f >> (s << 2))) & 15u;
}

// ---------- K0: table_logits = emb @ W + b (unchanged from R5) ----------
__global__ __launch_bounds__(256, 2) void k_table(const float* __restrict__ emb,
                                                  const float* __restrict__ W,
                                                  const float* __restrict__ bias,
                                                  float* __restrict__ table,
                                                  float* __restrict__ out) {
    if (blockIdx.x == 0 && threadIdx.x == 0) out[1] = 0.0f;
    __shared__ float WL[Hq * WLP];   // 60 KB
    const int tid = threadIdx.x;

    #pragma unroll
    for (int k = 0; k < 12; ++k) {
        int idx = tid + (k << 8);
        float4 v = *reinterpret_cast<const float4*>(W + idx * 4);
        *reinterpret_cast<float4*>(&WL[(idx >> 2) * WLP + ((idx & 3) << 2)]) = v;
    }
    __syncthreads();

    const int r_loc = tid >> 2;
    const int q     = tid & 3;
    const int v     = blockIdx.x * 64 + r_loc;
    const int vc    = v < Vq ? v : Vq - 1;
    const float* arow = emb + (size_t)vc * Hq;

    float acc[16];
    #pragma unroll
    for (int t = 0; t < 16; ++t) acc[t] = 0.0f;

    float4 buf[8];
    #pragma unroll
    for (int u = 0; u < 8; ++u)
        buf[u] = *reinterpret_cast<const float4*>(arow + (q + 4 * u) * 4);

    for (int k6 = 0; k6 < 6; ++k6) {
        #pragma unroll
        for (int u = 0; u < 8; ++u) {
            const int k = k6 * 8 + u;
            float4 av = buf[u];
            if (k + 8 < 48)
                buf[u] = *reinterpret_cast<const float4*>(arow + (q + 4 * (k + 8)) * 4);
            const int hb = (q + 4 * k) * 4;
            #pragma unroll
            for (int a = 0; a < 4; ++a) {
                float s = (a == 0) ? av.x : (a == 1) ? av.y : (a == 2) ? av.z : av.w;
                const float* wr = &WL[(hb + a) * WLP];
                float4 w0 = *reinterpret_cast<const float4*>(wr);
                float4 w1 = *reinterpret_cast<const float4*>(wr + 4);
                float4 w2 = *reinterpret_cast<const float4*>(wr + 8);
                float4 w3 = *reinterpret_cast<const float4*>(wr + 12);
                acc[0]  = fmaf(s, w0.x, acc[0]);
                acc[1]  = fmaf(s, w0.y, acc[1]);
                acc[2]  = fmaf(s, w0.z, acc[2]);
                acc[3]  = fmaf(s, w0.w, acc[3]);
                acc[4]  = fmaf(s, w1.x, acc[4]);
                acc[5]  = fmaf(s, w1.y, acc[5]);
                acc[6]  = fmaf(s, w1.z, acc[6]);
                acc[7]  = fmaf(s, w1.w, acc[7]);
                acc[8]  = fmaf(s, w2.x, acc[8]);
                acc[9]  = fmaf(s, w2.y, acc[9]);
                acc[10] = fmaf(s, w2.z, acc[10]);
                acc[11] = fmaf(s, w2.w, acc[11]);
                acc[12] = fmaf(s, w3.x, acc[12]);
                acc[13] = fmaf(s, w3.y, acc[13]);
                acc[14] = fmaf(s, w3.z, acc[14]);
                acc[15] = fmaf(s, w3.w, acc[15]);
            }
        }
    }
    #pragma unroll
    for (int t = 0; t < 16; ++t) {
        acc[t] += dpp_f<QX1>(acc[t]);
        acc[t] += dpp_f<QX2>(acc[t]);
    }
    if (v < Vq) {
        float4 bv = *reinterpret_cast<const float4*>(bias + q * 4);
        float4 o = make_float4(acc[q * 4] + bv.x, acc[q * 4 + 1] + bv.y,
                               acc[q * 4 + 2] + bv.z, acc[q * 4 + 3] + bv.w);
        *reinterpret_cast<float4*>(table + (size_t)v * Tq + q * 4) = o;
    }
}

// ---------- K1: CRF scans. grid=32, block=64: 4 batches/wave, state j in lane j of row ----------
// blocks 0..15: denominator+numerator (batches 4*blk..4*blk+3). blocks 16..31: viterbi.
// Per step each lane gathers all 16 states via 15 DPPs (2 dependent levels, row/quad local).

// fast DPP gather: slots 0..15; slot->state decoded by runtime probe into pm[]
#define G16_DPP(PV) \
      float r1 = dpp_f<QX1>(PV), r2 = dpp_f<QX2>(PV), r3 = dpp_f<QX3>(PV); \
      float r4 = dpp_f<RR4>(PV), r8v = dpp_f<RR8>(PV), r12v = dpp_f<RR12>(PV); \
      float r5 = dpp_f<QX1>(r4), r6 = dpp_f<QX2>(r4), r7 = dpp_f<QX3>(r4); \
      float r9 = dpp_f<QX1>(r8v), r10 = dpp_f<QX2>(r8v), r11 = dpp_f<QX3>(r8v); \
      float r13 = dpp_f<QX1>(r12v), r14 = dpp_f<QX2>(r12v), r15 = dpp_f<QX3>(r12v);

// fallback: explicit bpermute from row-base + pm[s]
#define G16_BP(PV) \
      const int rb_ = (lane & 48) << 2; \
      float r1 = bperm_f(PV, rb_ + (pm[1] << 2)),  r2 = bperm_f(PV, rb_ + (pm[2] << 2)); \
      float r3 = bperm_f(PV, rb_ + (pm[3] << 2)),  r4 = bperm_f(PV, rb_ + (pm[4] << 2)); \
      float r5 = bperm_f(PV, rb_ + (pm[5] << 2)),  r6 = bperm_f(PV, rb_ + (pm[6] << 2)); \
      float r7 = bperm_f(PV, rb_ + (pm[7] << 2)),  r8v = bperm_f(PV, rb_ + (pm[8] << 2)); \
      float r9 = bperm_f(PV, rb_ + (pm[9] << 2)),  r10 = bperm_f(PV, rb_ + (pm[10] << 2)); \
      float r11 = bperm_f(PV, rb_ + (pm[11] << 2)), r12v = bperm_f(PV, rb_ + (pm[12] << 2)); \
      float r13 = bperm_f(PV, rb_ + (pm[13] << 2)), r14 = bperm_f(PV, rb_ + (pm[14] << 2)); \
      float r15 = bperm_f(PV, rb_ + (pm[15] << 2));

#define DEN_BODY \
      float ff = __expf(em) * 0.0625f; \
      float a0 = P * Wt[0];    a0 = fmaf(r1, Wt[1], a0);   a0 = fmaf(r2, Wt[2], a0);   a0 = fmaf(r3, Wt[3], a0); \
      float a1 = r4 * Wt[4];   a1 = fmaf(r5, Wt[5], a1);   a1 = fmaf(r6, Wt[6], a1);   a1 = fmaf(r7, Wt[7], a1); \
      float a2 = r8v * Wt[8];  a2 = fmaf(r9, Wt[9], a2);   a2 = fmaf(r10, Wt[10], a2); a2 = fmaf(r11, Wt[11], a2); \
      float a3 = r12v * Wt[12]; a3 = fmaf(r13, Wt[13], a3); a3 = fmaf(r14, Wt[14], a3); a3 = fmaf(r15, Wt[15], a3); \
      P = ((a0 + a1) + (a2 + a3)) * ff;

#define VIT_BODY \
      float v0 = P + Wt[0],    v1 = r1 + Wt[1],   v2 = r2 + Wt[2],   v3 = r3 + Wt[3]; \
      float v4 = r4 + Wt[4],   v5 = r5 + Wt[5],   v6 = r6 + Wt[6],   v7 = r7 + Wt[7]; \
      float v8 = r8v + Wt[8],  v9 = r9 + Wt[9],   v10 = r10 + Wt[10], v11 = r11 + Wt[11]; \
      float v12 = r12v + Wt[12], v13 = r13 + Wt[13], v14 = r14 + Wt[14], v15 = r15 + Wt[15]; \
      float mv = fmaxf(fmaxf(fmaxf(fmaxf(v0, v1), fmaxf(v2, v3)), fmaxf(fmaxf(v4, v5), fmaxf(v6, v7))), \
                       fmaxf(fmaxf(fmaxf(v8, v9), fmaxf(v10, v11)), fmaxf(fmaxf(v12, v13), fmaxf(v14, v15)))); \
      int c0 = (v0 == mv) ? st[0] : 99,  c1 = (v1 == mv) ? st[1] : 99; \
      int c2 = (v2 == mv) ? st[2] : 99,  c3 = (v3 == mv) ? st[3] : 99; \
      int c4 = (v4 == mv) ? st[4] : 99,  c5 = (v5 == mv) ? st[5] : 99; \
      int c6 = (v6 == mv) ? st[6] : 99,  c7 = (v7 == mv) ? st[7] : 99; \
      int c8 = (v8 == mv) ? st[8] : 99,  c9 = (v9 == mv) ? st[9] : 99; \
      int c10 = (v10 == mv) ? st[10] : 99, c11 = (v11 == mv) ? st[11] : 99; \
      int c12 = (v12 == mv) ? st[12] : 99, c13 = (v13 == mv) ? st[13] : 99; \
      int c14 = (v14 == mv) ? st[14] : 99, c15 = (v15 == mv) ? st[15] : 99; \
      int li = min(min(min(min(c0, c1), min(c2, c3)), min(min(c4, c5), min(c6, c7))), \
                   min(min(min(c8, c9), min(c10, c11)), min(min(c12, c13), min(c14, c15)))); \
      P = mv + em; \
      hbase[(t - 1) * Tq] = (unsigned char)li;

#define SCAN_LOOP(GATHER, BODY) \
  for (int bi = 0; bi < 64; ++bi) { \
    _Pragma("unroll") \
    for (int u = 0; u < 8; ++u) { \
      const int t = 1 + bi * 8 + u; \
      if (t <= 511) { \
        float em = raw[u]; \
        { int tp = t + 8; if (tp > 511) tp = 511; \
          raw[u] = table[(size_t)srcl[(b4 << 9) + tp] * Tq + j]; } \
        GATHER(P); \
        BODY; \
      } \
    } \
  }

__global__ __launch_bounds__(64) void k_scan(const int* __restrict__ src,
                                             const int* __restrict__ label,
                                             const int* __restrict__ pmask,
                                             const float* __restrict__ table,
                                             const float* __restrict__ start_t,
                                             const float* __restrict__ end_t,
                                             const float* __restrict__ trans,
                                             float* __restrict__ nd,
                                             float* __restrict__ out) {
    __shared__ int srcl[4 * Sq];
    __shared__ int labl[4 * Sq];
    __shared__ __align__(16) unsigned char hist8[4 * Sq * Tq];   // 32 KB, row 511 = identity
    __shared__ __align__(8) unsigned char predi8[4 * Sq];

    const int lane = threadIdx.x;
    const int b4 = lane >> 4;          // batch within block
    const int j  = lane & 15;          // state
    const bool vit = blockIdx.x >= 16;
    const int bb = (vit ? blockIdx.x - 16 : blockIdx.x) * 4;
    const int batch = bb + b4;

    // stage src & label for 4 batches
    #pragma unroll
    for (int k = 0; k < 32; ++k) {
        int idx = lane + (k << 6);          // 0..2047
        int bb4 = idx >> 9, t = idx & 511;
        srcl[idx] = src[(bb + bb4) * Sq + t];
        labl[idx] = label[(bb + bb4) * Sq + t];
    }
    __syncthreads();

    // ---- probe the DPP network: decode slot -> state map pm[] ----
    int pm[16];
    bool fast;
    {
        float x = __int_as_float(j);
        G16_DPP(x);
        pm[0] = j;
        pm[1] = __float_as_int(r1);  pm[2] = __float_as_int(r2);  pm[3] = __float_as_int(r3);
        pm[4] = __float_as_int(r4);  pm[5] = __float_as_int(r5);  pm[6] = __float_as_int(r6);
        pm[7] = __float_as_int(r7);  pm[8] = __float_as_int(r8v); pm[9] = __float_as_int(r9);
        pm[10] = __float_as_int(r10); pm[11] = __float_as_int(r11); pm[12] = __float_as_int(r12v);
        pm[13] = __float_as_int(r13); pm[14] = __float_as_int(r14); pm[15] = __float_as_int(r15);
        u32 cov = 0;
        bool inr = true;
        #pragma unroll
        for (int s = 0; s < 16; ++s) {
            inr = inr && (pm[s] >= 0) && (pm[s] < 16);
            cov |= 1u << (pm[s] & 15);
        }
        fast = (__all((inr && cov == 0xFFFFu) ? 1 : 0) != 0);
        if (!fast) {
            pm[0] = j;
            #pragma unroll
            for (int s = 1; s < 16; ++s) pm[s] = (j + s) & 15;   // any bijection; bperm uses pm directly
        }
    }

    // weights + slot states
    float Wt[16];
    int st[16];
    #pragma unroll
    for (int s = 0; s < 16; ++s) {
        float tv = trans[pm[s] * Tq + j];
        Wt[s] = vit ? tv : __expf(tv);
        st[s] = pm[s];
    }

    // init state at t=0
    float em00 = table[(size_t)srcl[b4 << 9] * Tq + j];
    float P = vit ? (start_t[j] + em00) : __expf(start_t[j] + em00);

    // em prefetch ring (8 deep, static indices)
    float raw[8];
    #pragma unroll
    for (int u = 0; u < 8; ++u) {
        int t = 1 + u; if (t > 511) t = 511;
        raw[u] = table[(size_t)srcl[(b4 << 9) + t] * Tq + j];
    }

    unsigned char* hbase = hist8 + b4 * (Sq * Tq) + j;

    if (!vit) {
        if (fast) { SCAN_LOOP(G16_DPP, DEN_BODY) }
        else      { SCAN_LOOP(G16_BP, DEN_BODY) }

        // den = 511*ln16 + log(sum_j p_j * exp(end_j))   (row-16 sum)
        float val = P * __expf(end_t[j]);
        val += dpp_f<QX1>(val); val += dpp_f<QX2>(val);
        val += dpp_f<RR4>(val); val += dpp_f<RR8>(val);
        float den = (float)(511.0 * 2.7725887222397811) + __logf(val);

        // numerator: 16 lanes per batch, 32 timesteps each
        float numv = 0.0f;
        int sl = 0;
        #pragma unroll
        for (int k = 0; k < 32; ++k) {
            int t = j + (k << 4);
            int tag = labl[(b4 << 9) + t];
            int m = pmask[batch * Sq + t];
            sl += m;
            float emtt = table[(size_t)srcl[(b4 << 9) + t] * Tq + tag];
            if (t == 0) {
                numv += start_t[tag] + emtt;
            } else {
                int tp = labl[(b4 << 9) + t - 1];
                numv += (float)m * (trans[tp * Tq + tag] + emtt);
            }
        }
        numv += dpp_f<QX1>(numv); numv += dpp_f<QX2>(numv);
        numv += dpp_f<RR4>(numv); numv += dpp_f<RR8>(numv);
        sl += dpp_i<QX1>(sl); sl += dpp_i<QX2>(sl);
        sl += dpp_i<RR4>(sl); sl += dpp_i<RR8>(sl);
        if (j == 0) {
            int last = labl[(b4 << 9) + sl - 1];
            nd[batch] = (numv + end_t[last]) - den;
        }
    } else {
        if (fast) { SCAN_LOOP(G16_DPP, VIT_BODY) }
        else      { SCAN_LOOP(G16_BP, VIT_BODY) }

        // final argmax within each row (ties -> lowest state)
        float fv = P + end_t[j];
        int fi = j;
        #pragma unroll
        for (int off = 1; off < 16; off <<= 1) {
            float ov = __shfl_xor(fv, off);
            int oi = __shfl_xor(fi, off);
            bool take = (ov > fv) || (ov == fv && oi < fi);
            fv = take ? ov : fv;
            fi = take ? oi : fi;
        }
        if (lane < 16) {   // identity row 511 for each batch
            hist8[(0 << 13) + 511 * 16 + lane] = (unsigned char)lane;
            hist8[(1 << 13) + 511 * 16 + lane] = (unsigned char)lane;
            hist8[(2 << 13) + 511 * 16 + lane] = (unsigned char)lane;
            hist8[(3 << 13) + 511 * 16 + lane] = (unsigned char)lane;
        }
        __syncthreads();

        // ===== backtrack via function-composition scan, per batch =====
        #pragma unroll
        for (int b4i = 0; b4i < 4; ++b4i) {
            const unsigned char* hb = hist8 + (b4i << 13);
            u64 rp[8];
            #pragma unroll
            for (int k = 0; k < 8; ++k) {
                uint4 rw = *reinterpret_cast<const uint4*>(hb + ((lane * 8 + k) << 4));
                u32 lo = packnib(rw.x) | (packnib(rw.y) << 16);
                u32 hi = packnib(rw.z) | (packnib(rw.w) << 16);
                rp[k] = (u64)lo | ((u64)hi << 32);
            }
            u64 F = rp[7];
            #pragma unroll
            for (int k = 6; k >= 0; --k) {
                u64 nf = 0;
                #pragma unroll
                for (int e = 0; e < 16; ++e) {
                    u32 s = (u32)(F >> (e * 4)) & 15u;
                    nf |= ((u64)nib64(rp[k], s)) << (e * 4);
                }
                F = nf;
            }
            u32 Flo = (u32)F, Fhi = (u32)(F >> 32);

            u32 pk[8] = {0, 0, 0, 0, 0, 0, 0, 0};
            u32 E = (u32)__builtin_amdgcn_readlane(fi, b4i * 16);
            #pragma unroll 64
            for (int c = 63; c >= 0; --c) {
                u64 Fc = ((u64)(u32)__builtin_amdgcn_readlane((int)Fhi, c) << 32)
                       | (u64)(u32)__builtin_amdgcn_readlane((int)Flo, c);
                pk[c >> 3] |= E << ((c & 7) * 4);
                E = nib64(Fc, E);
            }

            u32 a0 = (lane & 8) ? pk[1] : pk[0];
            u32 a1 = (lane & 8) ? pk[3] : pk[2];
            u32 a2 = (lane & 8) ? pk[5] : pk[4];
            u32 a3 = (lane & 8) ? pk[7] : pk[6];
            u32 b0 = (lane & 16) ? a1 : a0;
            u32 b1 = (lane & 16) ? a3 : a2;
            u32 c0s = (lane & 32) ? b1 : b0;
            u32 cur = (c0s >> ((lane & 7) * 4)) & 15u;
            u32 w0 = 0, w1 = 0;
            #pragma unroll
            for (int k = 7; k >= 0; --k) {
                cur = nib64(rp[k], cur);
                if (k >= 4) w1 |= cur << ((k - 4) * 8);
                else        w0 |= cur << (k * 8);
            }
            *reinterpret_cast<uint2*>(&predi8[(b4i << 9) + lane * 8]) = make_uint2(w0, w1);
        }
        __syncthreads();

        // ================= outputs =================
        int cnt = 0;
        #pragma unroll
        for (int b4i = 0; b4i < 4; ++b4i) {
            #pragma unroll
            for (int k = 0; k < 8; ++k) {
                int s_ = lane + (k << 6);
                int lab = labl[(b4i << 9) + s_];
                int pr = (int)predi8[(b4i << 9) + s_];
                int mpr = lab > 0 ? pr : 0;
                out[2 + (bb + b4i) * Sq + s_] = (float)mpr;
                out[2 + Bq * Sq + (bb + b4i) * Sq + s_] = (float)lab;
                cnt += (mpr == lab) ? 1 : 0;
            }
        }
        #pragma unroll
        for (int off = 1; off < 64; off <<= 1) cnt += __shfl_xor(cnt, off);
        if (lane == 0) atomicAdd(out + 1, (float)cnt);
    }
}

// ---------- K2: loss = -(sum_b nd[b]) / B ----------
__global__ __launch_bounds__(64) void k_final(const float* __restrict__ nd,
                                              float* __restrict__ out) {
    float v = nd[threadIdx.x];
    #pragma unroll
    for (int off = 1; off < 64; off <<= 1) v += __shfl_xor(v, off);
    if (threadIdx.x == 0) out[0] = -v * (1.0f / (float)Bq);
}

extern "C" void kernel_launch(void* const* d_in, const int* in_sizes, int n_in,
                              void* d_out, int out_size, void* d_ws, size_t ws_size,
                              hipStream_t stream) {
    const int*   src   = (const int*)d_in[0];
    const int*   label = (const int*)d_in[1];
    const int*   pmask = (const int*)d_in[2];
    const float* emb   = (const float*)d_in[3];
    const float* W     = (const float*)d_in[4];
    const float* bias  = (const float*)d_in[5];
    const float* st    = (const float*)d_in[6];
    const float* en    = (const float*)d_in[7];
    const float* tr    = (const float*)d_in[8];
    float* out = (float*)d_out;

    float* table = (float*)d_ws;
    float* nd    = table + (size_t)Vq * Tq;

    const int nblk = (Vq + 63) / 64;   // 477
    k_table<<<nblk, 256, 0, stream>>>(emb, W, bias, table, out);
    k_scan<<<32, 64, 0, stream>>>(src, label, pmask, table, st, en, tr, nd, out);
    k_final<<<1, 64, 0, stream>>>(nd, out);
}

// Round 8
// 97.456 us; speedup vs baseline: 1.4344x; 1.4344x over previous
//
#include <hip/hip_runtime.h>

#define Bq 64
#define Sq 512
#define Hq 768
#define Tq 16
#define Vq 30522
#define EMP 516   // em row stride (pad: 2-way banks = free)
#define WLP 20    // W LDS row stride in k_table

typedef unsigned int u32;
typedef unsigned long long u64;
typedef unsigned char u8;

// ---------- cross-lane helpers ----------
__device__ __forceinline__ float bperm_f(float v, int byteidx) {
    return __int_as_float(__builtin_amdgcn_ds_bpermute(byteidx, __float_as_int(v)));
}
template <int CTRL>
__device__ __forceinline__ int dpp_i(int v) {
    return __builtin_amdgcn_mov_dpp(v, CTRL, 0xF, 0xF, true);
}
template <int CTRL>
__device__ __forceinline__ float dpp_f(float v) {
    return __int_as_float(dpp_i<CTRL>(__float_as_int(v)));
}

#define QX1 0xB1   // quad_perm [1,0,3,2]
#define QX2 0x4E   // quad_perm [2,3,0,1]
#define QX3 0x1B   // quad_perm [3,2,1,0]
#define RR4  0x124 // row_ror:4
#define RR8  0x128 // row_ror:8
#define RR12 0x12C // row_ror:12

__device__ __forceinline__ u32 packnib(u32 d) {
    u32 y = d | (d >> 4);
    y &= 0x00FF00FFu;
    y = (y | (y >> 8)) & 0xFFFFu;
    return y;
}
__device__ __forceinline__ u32 nib64(u64 f, u32 s) {
    return ((u32)(f >> (s << 2))) & 15u;
}

// ---------- K0: table_logits = emb @ W + b (validated R5 version) ----------
__global__ __launch_bounds__(256, 2) void k_table(const float* __restrict__ emb,
                                                  const float* __restrict__ W,
                                                  const float* __restrict__ bias,
                                                  float* __restrict__ table,
                                                  float* __restrict__ out) {
    if (blockIdx.x == 0 && threadIdx.x == 0) out[1] = 0.0f;
    __shared__ float WL[Hq * WLP];
    const int tid = threadIdx.x;

    #pragma unroll
    for (int k = 0; k < 12; ++k) {
        int idx = tid + (k << 8);
        float4 v = *reinterpret_cast<const float4*>(W + idx * 4);
        *reinterpret_cast<float4*>(&WL[(idx >> 2) * WLP + ((idx & 3) << 2)]) = v;
    }
    __syncthreads();

    const int r_loc = tid >> 2;
    const int q     = tid & 3;
    const int v     = blockIdx.x * 64 + r_loc;
    const int vc    = v < Vq ? v : Vq - 1;
    const float* arow = emb + (size_t)vc * Hq;

    float acc[16];
    #pragma unroll
    for (int t = 0; t < 16; ++t) acc[t] = 0.0f;

    float4 buf[8];
    #pragma unroll
    for (int u = 0; u < 8; ++u)
        buf[u] = *reinterpret_cast<const float4*>(arow + (q + 4 * u) * 4);

    for (int k6 = 0; k6 < 6; ++k6) {
        #pragma unroll
        for (int u = 0; u < 8; ++u) {
            const int k = k6 * 8 + u;
            float4 av = buf[u];
            if (k + 8 < 48)
                buf[u] = *reinterpret_cast<const float4*>(arow + (q + 4 * (k + 8)) * 4);
            const int hb = (q + 4 * k) * 4;
            #pragma unroll
            for (int a = 0; a < 4; ++a) {
                float s = (a == 0) ? av.x : (a == 1) ? av.y : (a == 2) ? av.z : av.w;
                const float* wr = &WL[(hb + a) * WLP];
                float4 w0 = *reinterpret_cast<const float4*>(wr);
                float4 w1 = *reinterpret_cast<const float4*>(wr + 4);
                float4 w2 = *reinterpret_cast<const float4*>(wr + 8);
                float4 w3 = *reinterpret_cast<const float4*>(wr + 12);
                acc[0]  = fmaf(s, w0.x, acc[0]);
                acc[1]  = fmaf(s, w0.y, acc[1]);
                acc[2]  = fmaf(s, w0.z, acc[2]);
                acc[3]  = fmaf(s, w0.w, acc[3]);
                acc[4]  = fmaf(s, w1.x, acc[4]);
                acc[5]  = fmaf(s, w1.y, acc[5]);
                acc[6]  = fmaf(s, w1.z, acc[6]);
                acc[7]  = fmaf(s, w1.w, acc[7]);
                acc[8]  = fmaf(s, w2.x, acc[8]);
                acc[9]  = fmaf(s, w2.y, acc[9]);
                acc[10] = fmaf(s, w2.z, acc[10]);
                acc[11] = fmaf(s, w2.w, acc[11]);
                acc[12] = fmaf(s, w3.x, acc[12]);
                acc[13] = fmaf(s, w3.y, acc[13]);
                acc[14] = fmaf(s, w3.z, acc[14]);
                acc[15] = fmaf(s, w3.w, acc[15]);
            }
        }
    }
    #pragma unroll
    for (int t = 0; t < 16; ++t) {
        acc[t] += dpp_f<QX1>(acc[t]);
        acc[t] += dpp_f<QX2>(acc[t]);
    }
    if (v < Vq) {
        float4 bv = *reinterpret_cast<const float4*>(bias + q * 4);
        float4 o = make_float4(acc[q * 4] + bv.x, acc[q * 4 + 1] + bv.y,
                               acc[q * 4 + 2] + bv.z, acc[q * 4 + 3] + bv.w);
        *reinterpret_cast<float4*>(table + (size_t)v * Tq + q * 4) = o;
    }
}

// ---------- gather macros (16-lane row broadcast layout) ----------
#define G16_DPP(PV) \
      float r1 = dpp_f<QX1>(PV), r2 = dpp_f<QX2>(PV), r3 = dpp_f<QX3>(PV); \
      float r4 = dpp_f<RR4>(PV), r8v = dpp_f<RR8>(PV), r12v = dpp_f<RR12>(PV); \
      float r5 = dpp_f<QX1>(r4), r6 = dpp_f<QX2>(r4), r7 = dpp_f<QX3>(r4); \
      float r9 = dpp_f<QX1>(r8v), r10 = dpp_f<QX2>(r8v), r11 = dpp_f<QX3>(r8v); \
      float r13 = dpp_f<QX1>(r12v), r14 = dpp_f<QX2>(r12v), r15 = dpp_f<QX3>(r12v);

#define G16_BP(PV) \
      const int rb_ = (lane & 48) << 2; \
      float r1 = bperm_f(PV, rb_ + (pm[1] << 2)),  r2 = bperm_f(PV, rb_ + (pm[2] << 2)); \
      float r3 = bperm_f(PV, rb_ + (pm[3] << 2)),  r4 = bperm_f(PV, rb_ + (pm[4] << 2)); \
      float r5 = bperm_f(PV, rb_ + (pm[5] << 2)),  r6 = bperm_f(PV, rb_ + (pm[6] << 2)); \
      float r7 = bperm_f(PV, rb_ + (pm[7] << 2)),  r8v = bperm_f(PV, rb_ + (pm[8] << 2)); \
      float r9 = bperm_f(PV, rb_ + (pm[9] << 2)),  r10 = bperm_f(PV, rb_ + (pm[10] << 2)); \
      float r11 = bperm_f(PV, rb_ + (pm[11] << 2)), r12v = bperm_f(PV, rb_ + (pm[12] << 2)); \
      float r13 = bperm_f(PV, rb_ + (pm[13] << 2)), r14 = bperm_f(PV, rb_ + (pm[14] << 2)); \
      float r15 = bperm_f(PV, rb_ + (pm[15] << 2));

// den step: P' = (sum_s r_s * Wt[s]) * ff
#define DEN_BODY(ff) \
      float a0 = P * Wt[0];     a0 = fmaf(r1, Wt[1], a0);   a0 = fmaf(r2, Wt[2], a0);   a0 = fmaf(r3, Wt[3], a0); \
      float a1 = r4 * Wt[4];    a1 = fmaf(r5, Wt[5], a1);   a1 = fmaf(r6, Wt[6], a1);   a1 = fmaf(r7, Wt[7], a1); \
      float a2 = r8v * Wt[8];   a2 = fmaf(r9, Wt[9], a2);   a2 = fmaf(r10, Wt[10], a2); a2 = fmaf(r11, Wt[11], a2); \
      float a3 = r12v * Wt[12]; a3 = fmaf(r13, Wt[13], a3); a3 = fmaf(r14, Wt[14], a3); a3 = fmaf(r15, Wt[15], a3); \
      P = ((a0 + a1) + (a2 + a3)) * (ff);

#define DEN_STEP_F(ff) { G16_DPP(P); DEN_BODY(ff) }
#define DEN_STEP_B(ff) { G16_BP(P);  DEN_BODY(ff) }

// vit step (lean, no argmax): P' = max_s(r_s + Wt[s]) + em; store sc
#define VIT_BODY(emv, tcur) \
      float v0 = P + Wt[0],     v1 = r1 + Wt[1],    v2 = r2 + Wt[2],    v3 = r3 + Wt[3]; \
      float v4 = r4 + Wt[4],    v5 = r5 + Wt[5],    v6 = r6 + Wt[6],    v7 = r7 + Wt[7]; \
      float v8 = r8v + Wt[8],   v9 = r9 + Wt[9],    v10 = r10 + Wt[10], v11 = r11 + Wt[11]; \
      float v12 = r12v + Wt[12], v13 = r13 + Wt[13], v14 = r14 + Wt[14], v15 = r15 + Wt[15]; \
      float ma = fmaxf(fmaxf(v0, v1), v2),  mb = fmaxf(fmaxf(v3, v4), v5); \
      float mc = fmaxf(fmaxf(v6, v7), v8),  md = fmaxf(fmaxf(v9, v10), v11); \
      float me = fmaxf(fmaxf(v12, v13), v14); \
      float mv = fmaxf(fmaxf(fmaxf(ma, mb), mc), fmaxf(fmaxf(md, me), v15)); \
      P = mv + (emv); \
      if (lane < 16) scb[(tcur) * Tq + j] = P;

#define VIT_STEP_F(emv, tcur) { G16_DPP(P); VIT_BODY(emv, tcur) }
#define VIT_STEP_B(emv, tcur) { G16_BP(P);  VIT_BODY(emv, tcur) }

#define SCAN4(STEP, X1, X2, X3) \
      STEP(f0.X1, 1) STEP(f0.X2, 2) STEP(f0.X3, 3) \
      { float4 fc = emrow[1]; \
        for (int t0 = 4; t0 < Sq; t0 += 4) { \
            float4 fn; \
            if (t0 + 4 < Sq) fn = emrow[(t0 >> 2) + 1]; \
            STEP(fc.x, t0) STEP(fc.y, t0 + 1) STEP(fc.z, t0 + 2) STEP(fc.w, t0 + 3) \
            fc = fn; \
        } }

// den variant ignores tcur
#define DSTEP_F(emv, tcur) DEN_STEP_F(emv)
#define DSTEP_B(emv, tcur) DEN_STEP_B(emv)

// ---------- K1: CRF scans. grid=96, block=64 (1 wave). ----------
// blocks 0..31:  den, 2 batches each. blocks 32..95: vit, 1 batch each.
__global__ __launch_bounds__(64) void k_scan(const int* __restrict__ src,
                                             const int* __restrict__ label,
                                             const int* __restrict__ pmask,
                                             const float* __restrict__ table,
                                             const float* __restrict__ start_t,
                                             const float* __restrict__ end_t,
                                             const float* __restrict__ trans,
                                             float* __restrict__ nd,
                                             float* __restrict__ out) {
    __shared__ __align__(16) char smem[78848];

    const int lane = threadIdx.x;
    const int j  = lane & 15;          // state
    const int b4 = lane >> 4;          // row
    const bool vit = blockIdx.x >= 32;

    // ---- probe the DPP network: decode slot -> state map pm[] ----
    int pm[16];
    bool fast;
    {
        float x = __int_as_float(j);
        G16_DPP(x);
        pm[0] = j;
        pm[1] = __float_as_int(r1);   pm[2] = __float_as_int(r2);   pm[3] = __float_as_int(r3);
        pm[4] = __float_as_int(r4);   pm[5] = __float_as_int(r5);   pm[6] = __float_as_int(r6);
        pm[7] = __float_as_int(r7);   pm[8] = __float_as_int(r8v);  pm[9] = __float_as_int(r9);
        pm[10] = __float_as_int(r10); pm[11] = __float_as_int(r11); pm[12] = __float_as_int(r12v);
        pm[13] = __float_as_int(r13); pm[14] = __float_as_int(r14); pm[15] = __float_as_int(r15);
        u32 cov = 0;
        bool inr = true;
        #pragma unroll
        for (int s = 0; s < 16; ++s) {
            inr = inr && (pm[s] >= 0) && (pm[s] < 16);
            cov |= 1u << (pm[s] & 15);
        }
        fast = (__all((inr && cov == 0xFFFFu) ? 1 : 0) != 0);
        if (!fast) {
            pm[0] = j;
            #pragma unroll
            for (int s = 1; s < 16; ++s) pm[s] = (j + s) & 15;
        }
    }

    if (!vit) {
        // ====================== DENOMINATOR (2 batches/wave) ======================
        float* emT = (float*)smem;                    // [2*16][EMP] FF values
        int* srcl  = (int*)(smem + 66048);            // [2][512]
        int* labl  = (int*)(smem + 70144);            // [2][512]
        const int bb = blockIdx.x * 2;
        const int bm = b4 & 1;
        const int batch = bb + bm;

        #pragma unroll
        for (int k = 0; k < 16; ++k) {
            int idx = lane + (k << 6);                // 0..1023
            int bch = idx >> 9, t = idx & 511;
            srcl[idx] = src[(bb + bch) * Sq + t];
            labl[idx] = label[(bb + bch) * Sq + t];
        }
        __syncthreads();
        #pragma unroll 4
        for (int k = 0; k < 256; ++k) {
            int idx = lane + (k << 6);                // 0..16383
            int bch = idx >> 13, rem = idx & 8191;
            int t = rem >> 4, jj = rem & 15;
            emT[(bch * 16 + jj) * EMP + t] =
                __expf(table[(size_t)srcl[(bch << 9) + t] * Tq + jj]) * 0.0625f;
        }
        __syncthreads();

        float Wt[16];
        #pragma unroll
        for (int s = 0; s < 16; ++s) Wt[s] = __expf(trans[pm[s] * Tq + j]);

        const float4* emrow = reinterpret_cast<const float4*>(emT + (bm * 16 + j) * EMP);
        float4 f0 = emrow[0];
        float P = __expf(start_t[j]) * f0.x * 16.0f;
        float* scb = nullptr; (void)scb;

        if (fast) { SCAN4(DSTEP_F, y, z, w) }
        else      { SCAN4(DSTEP_B, y, z, w) }

        float val = P * __expf(end_t[j]);
        val += dpp_f<QX1>(val); val += dpp_f<QX2>(val);
        val += dpp_f<RR4>(val); val += dpp_f<RR8>(val);
        float den = (float)(511.0 * 2.7725887222397811) + __logf(val);

        // numerator: 16 lanes per batch row
        float numv = 0.0f;
        int sl = 0;
        #pragma unroll
        for (int k = 0; k < 32; ++k) {
            int t = j + (k << 4);
            int tag = labl[(bm << 9) + t];
            int m = pmask[batch * Sq + t];
            sl += m;
            float emtt = table[(size_t)srcl[(bm << 9) + t] * Tq + tag];
            if (t == 0) {
                numv += start_t[tag] + emtt;
            } else {
                int tp = labl[(bm << 9) + t - 1];
                numv += (float)m * (trans[tp * Tq + tag] + emtt);
            }
        }
        numv += dpp_f<QX1>(numv); numv += dpp_f<QX2>(numv);
        numv += dpp_f<RR4>(numv); numv += dpp_f<RR8>(numv);
        sl += dpp_i<QX1>(sl); sl += dpp_i<QX2>(sl);
        sl += dpp_i<RR4>(sl); sl += dpp_i<RR8>(sl);
        if (j == 0 && b4 < 2) {
            int last = labl[(bm << 9) + sl - 1];
            nd[batch] = (numv + end_t[last]) - den;
        }
    } else {
        // ====================== VITERBI (1 batch/wave) ======================
        float* em   = (float*)smem;                   // [16][EMP] raw logits
        float* scb  = (float*)(smem + 33024);         // [512][16] score trajectory
        u8*  hist   = (u8*)(smem + 65792);            // [512][16]
        int* srcl   = (int*)(smem + 73984);           // [512]
        int* labl   = (int*)(smem + 76032);           // [512]
        u8*  predi  = (u8*)(smem + 78080);            // [512]
        const int batch = blockIdx.x - 32;

        #pragma unroll
        for (int k = 0; k < 8; ++k) {
            int t = lane + (k << 6);
            srcl[t] = src[batch * Sq + t];
            labl[t] = label[batch * Sq + t];
        }
        __syncthreads();
        #pragma unroll 4
        for (int k = 0; k < 128; ++k) {
            int idx = lane + (k << 6);
            int t = idx >> 4, jj = idx & 15;
            em[jj * EMP + t] = table[(size_t)srcl[t] * Tq + jj];
        }
        __syncthreads();

        float Wt[16];
        #pragma unroll
        for (int s = 0; s < 16; ++s) Wt[s] = trans[pm[s] * Tq + j];

        const float4* emrow = reinterpret_cast<const float4*>(em + j * EMP);
        float4 f0 = emrow[0];
        float P = start_t[j] + f0.x;
        if (lane < 16) scb[j] = P;

        if (fast) { SCAN4(VIT_STEP_F, y, z, w) }
        else      { SCAN4(VIT_STEP_B, y, z, w) }

        // final argmax within row (ties -> lowest state)
        float fv = P + end_t[j];
        int fi = j;
        #pragma unroll
        for (int off = 1; off < 16; off <<= 1) {
            float ov = __shfl_xor(fv, off);
            int oi = __shfl_xor(fi, off);
            bool take = (ov > fv) || (ov == fv && oi < fi);
            fv = take ? ov : fv;
            fi = take ? oi : fi;
        }
        __syncthreads();

        // ===== parallel post-pass: recompute hist rows (exact replay) =====
        {
            float Tt[16];
            #pragma unroll
            for (int m = 0; m < 16; ++m) Tt[m] = trans[m * Tq + j];
            const int r = b4;
            for (int k = 0; k < 128; ++k) {
                int t = 1 + r + 4 * k;
                if (t < Sq) {
                    const float4* sr = reinterpret_cast<const float4*>(scb + (t - 1) * Tq);
                    float4 s0 = sr[0], s1 = sr[1], s2 = sr[2], s3 = sr[3];
                    float w0 = s0.x + Tt[0],  w1 = s0.y + Tt[1],  w2 = s0.z + Tt[2],  w3 = s0.w + Tt[3];
                    float w4 = s1.x + Tt[4],  w5 = s1.y + Tt[5],  w6 = s1.z + Tt[6],  w7 = s1.w + Tt[7];
                    float w8 = s2.x + Tt[8],  w9 = s2.y + Tt[9],  wA = s2.z + Tt[10], wB = s2.w + Tt[11];
                    float wC = s3.x + Tt[12], wD = s3.y + Tt[13], wE = s3.z + Tt[14], wF = s3.w + Tt[15];
                    float ma = fmaxf(fmaxf(w0, w1), w2),  mb = fmaxf(fmaxf(w3, w4), w5);
                    float mc = fmaxf(fmaxf(w6, w7), w8),  md = fmaxf(fmaxf(w9, wA), wB);
                    float me = fmaxf(fmaxf(wC, wD), wE);
                    float mv = fmaxf(fmaxf(fmaxf(ma, mb), mc), fmaxf(fmaxf(md, me), wF));
                    // exact argmax: gap==0 -> y=i ; gap>=1 ulp -> y>=~1e24 >> 15
                    float y0 = fmaf(mv - w0, 1e30f, 0.0f),  y1 = fmaf(mv - w1, 1e30f, 1.0f);
                    float y2 = fmaf(mv - w2, 1e30f, 2.0f),  y3 = fmaf(mv - w3, 1e30f, 3.0f);
                    float y4 = fmaf(mv - w4, 1e30f, 4.0f),  y5 = fmaf(mv - w5, 1e30f, 5.0f);
                    float y6 = fmaf(mv - w6, 1e30f, 6.0f),  y7 = fmaf(mv - w7, 1e30f, 7.0f);
                    float y8 = fmaf(mv - w8, 1e30f, 8.0f),  y9 = fmaf(mv - w9, 1e30f, 9.0f);
                    float yA = fmaf(mv - wA, 1e30f, 10.0f), yB = fmaf(mv - wB, 1e30f, 11.0f);
                    float yC = fmaf(mv - wC, 1e30f, 12.0f), yD = fmaf(mv - wD, 1e30f, 13.0f);
                    float yE = fmaf(mv - wE, 1e30f, 14.0f), yF = fmaf(mv - wF, 1e30f, 15.0f);
                    float na = fminf(fminf(y0, y1), y2),  nb = fminf(fminf(y3, y4), y5);
                    float nc = fminf(fminf(y6, y7), y8),  nd2 = fminf(fminf(y9, yA), yB);
                    float ne = fminf(fminf(yC, yD), yE);
                    float ym = fminf(fminf(fminf(na, nb), nc), fminf(fminf(nd2, ne), yF));
                    hist[(t - 1) * Tq + j] = (unsigned char)(int)ym;
                }
            }
        }
        if (lane < 16) hist[511 * Tq + lane] = (u8)lane;  // identity row
        __syncthreads();

        // ===== backtrack via function-composition scan =====
        u64 rp[8];
        #pragma unroll
        for (int k = 0; k < 8; ++k) {
            uint4 rw = *reinterpret_cast<const uint4*>(&hist[(lane * 8 + k) * Tq]);
            u32 lo = packnib(rw.x) | (packnib(rw.y) << 16);
            u32 hi = packnib(rw.z) | (packnib(rw.w) << 16);
            rp[k] = (u64)lo | ((u64)hi << 32);
        }
        u64 F = rp[7];
        #pragma unroll
        for (int k = 6; k >= 0; --k) {
            u64 nf = 0;
            #pragma unroll
            for (int e = 0; e < 16; ++e) {
                u32 s = (u32)(F >> (e * 4)) & 15u;
                nf |= ((u64)nib64(rp[k], s)) << (e * 4);
            }
            F = nf;
        }
        u32 Flo = (u32)F, Fhi = (u32)(F >> 32);

        u32 pk[8] = {0, 0, 0, 0, 0, 0, 0, 0};
        u32 E = (u32)__builtin_amdgcn_readlane(fi, 0) & 15u;
        #pragma unroll 64
        for (int c = 63; c >= 0; --c) {
            u64 Fc = ((u64)(u32)__builtin_amdgcn_readlane((int)Fhi, c) << 32)
                   | (u64)(u32)__builtin_amdgcn_readlane((int)Flo, c);
            pk[c >> 3] |= E << ((c & 7) * 4);
            E = nib64(Fc, E);
        }

        u32 a0s = (lane & 8) ? pk[1] : pk[0];
        u32 a1s = (lane & 8) ? pk[3] : pk[2];
        u32 a2s = (lane & 8) ? pk[5] : pk[4];
        u32 a3s = (lane & 8) ? pk[7] : pk[6];
        u32 b0s = (lane & 16) ? a1s : a0s;
        u32 b1s = (lane & 16) ? a3s : a2s;
        u32 c0s = (lane & 32) ? b1s : b0s;
        u32 cur = (c0s >> ((lane & 7) * 4)) & 15u;
        u32 w0 = 0, w1 = 0;
        #pragma unroll
        for (int k = 7; k >= 0; --k) {
            cur = nib64(rp[k], cur);
            if (k >= 4) w1 |= cur << ((k - 4) * 8);
            else        w0 |= cur << (k * 8);
        }
        *reinterpret_cast<uint2*>(&predi[lane * 8]) = make_uint2(w0, w1);
        __syncthreads();

        // outputs
        int cnt = 0;
        #pragma unroll
        for (int k = 0; k < 8; ++k) {
            int s_ = lane + (k << 6);
            int lab = labl[s_];
            int pr = (int)predi[s_];
            int mpr = lab > 0 ? pr : 0;
            out[2 + batch * Sq + s_] = (float)mpr;
            out[2 + Bq * Sq + batch * Sq + s_] = (float)lab;
            cnt += (mpr == lab) ? 1 : 0;
        }
        #pragma unroll
        for (int off = 1; off < 64; off <<= 1) cnt += __shfl_xor(cnt, off);
        if (lane == 0) atomicAdd(out + 1, (float)cnt);
    }
}

// ---------- K2: loss = -(sum_b nd[b]) / B ----------
__global__ __launch_bounds__(64) void k_final(const float* __restrict__ nd,
                                              float* __restrict__ out) {
    float v = nd[threadIdx.x];
    #pragma unroll
    for (int off = 1; off < 64; off <<= 1) v += __shfl_xor(v, off);
    if (threadIdx.x == 0) out[0] = -v * (1.0f / (float)Bq);
}

extern "C" void kernel_launch(void* const* d_in, const int* in_sizes, int n_in,
                              void* d_out, int out_size, void* d_ws, size_t ws_size,
                              hipStream_t stream) {
    const int*   src   = (const int*)d_in[0];
    const int*   label = (const int*)d_in[1];
    const int*   pmask = (const int*)d_in[2];
    const float* emb   = (const float*)d_in[3];
    const float* W     = (const float*)d_in[4];
    const float* bias  = (const float*)d_in[5];
    const float* st    = (const float*)d_in[6];
    const float* en    = (const float*)d_in[7];
    const float* tr    = (const float*)d_in[8];
    float* out = (float*)d_out;

    float* table = (float*)d_ws;
    float* nd    = table + (size_t)Vq * Tq;

    const int nblk = (Vq + 63) / 64;   // 477
    k_table<<<nblk, 256, 0, stream>>>(emb, W, bias, table, out);
    k_scan<<<96, 64, 0, stream>>>(src, label, pmask, table, st, en, tr, nd, out);
    k_final<<<1, 64, 0, stream>>>(nd, out);
}

// Round 9
// 91.600 us; speedup vs baseline: 1.5260x; 1.0639x over previous
//
#include <hip/hip_runtime.h>

#define Bq 64
#define Sq 512
#define Hq 768
#define Tq 16
#define Vq 30522
#define EMP 516   // em row stride (pad: 2-way banks = free)
#define WLP 20    // W LDS row stride in k_table

typedef unsigned int u32;
typedef unsigned long long u64;
typedef unsigned char u8;

// ---------- cross-lane helpers ----------
__device__ __forceinline__ float bperm_f(float v, int byteidx) {
    return __int_as_float(__builtin_amdgcn_ds_bpermute(byteidx, __float_as_int(v)));
}
template <int CTRL>
__device__ __forceinline__ int dpp_i(int v) {
    return __builtin_amdgcn_mov_dpp(v, CTRL, 0xF, 0xF, true);
}
template <int CTRL>
__device__ __forceinline__ float dpp_f(float v) {
    return __int_as_float(dpp_i<CTRL>(__float_as_int(v)));
}
template <int N>
__device__ __forceinline__ float ror_f(float v) {      // row_ror:N (within 16-lane row)
    return __int_as_float(__builtin_amdgcn_mov_dpp(__float_as_int(v), 0x120 + N, 0xF, 0xF, true));
}

#define QX1 0xB1
#define QX2 0x4E
#define RR4  0x124
#define RR8  0x128

__device__ __forceinline__ u32 packnib(u32 d) {
    u32 y = d | (d >> 4);
    y &= 0x00FF00FFu;
    y = (y | (y >> 8)) & 0xFFFFu;
    return y;
}
__device__ __forceinline__ u32 nib64(u64 f, u32 s) {
    return ((u32)(f >> (s << 2))) & 15u;
}

// ---------- K0: table_logits = emb @ W + b (validated R5 version; also zeroes out[0..1]) ----------
__global__ __launch_bounds__(256, 2) void k_table(const float* __restrict__ emb,
                                                  const float* __restrict__ W,
                                                  const float* __restrict__ bias,
                                                  float* __restrict__ table,
                                                  float* __restrict__ out) {
    if (blockIdx.x == 0 && threadIdx.x == 0) { out[0] = 0.0f; out[1] = 0.0f; }
    __shared__ float WL[Hq * WLP];
    const int tid = threadIdx.x;

    #pragma unroll
    for (int k = 0; k < 12; ++k) {
        int idx = tid + (k << 8);
        float4 v = *reinterpret_cast<const float4*>(W + idx * 4);
        *reinterpret_cast<float4*>(&WL[(idx >> 2) * WLP + ((idx & 3) << 2)]) = v;
    }
    __syncthreads();

    const int r_loc = tid >> 2;
    const int q     = tid & 3;
    const int v     = blockIdx.x * 64 + r_loc;
    const int vc    = v < Vq ? v : Vq - 1;
    const float* arow = emb + (size_t)vc * Hq;

    float acc[16];
    #pragma unroll
    for (int t = 0; t < 16; ++t) acc[t] = 0.0f;

    float4 buf[8];
    #pragma unroll
    for (int u = 0; u < 8; ++u)
        buf[u] = *reinterpret_cast<const float4*>(arow + (q + 4 * u) * 4);

    for (int k6 = 0; k6 < 6; ++k6) {
        #pragma unroll
        for (int u = 0; u < 8; ++u) {
            const int k = k6 * 8 + u;
            float4 av = buf[u];
            if (k + 8 < 48)
                buf[u] = *reinterpret_cast<const float4*>(arow + (q + 4 * (k + 8)) * 4);
            const int hb = (q + 4 * k) * 4;
            #pragma unroll
            for (int a = 0; a < 4; ++a) {
                float s = (a == 0) ? av.x : (a == 1) ? av.y : (a == 2) ? av.z : av.w;
                const float* wr = &WL[(hb + a) * WLP];
                float4 w0 = *reinterpret_cast<const float4*>(wr);
                float4 w1 = *reinterpret_cast<const float4*>(wr + 4);
                float4 w2 = *reinterpret_cast<const float4*>(wr + 8);
                float4 w3 = *reinterpret_cast<const float4*>(wr + 12);
                acc[0]  = fmaf(s, w0.x, acc[0]);
                acc[1]  = fmaf(s, w0.y, acc[1]);
                acc[2]  = fmaf(s, w0.z, acc[2]);
                acc[3]  = fmaf(s, w0.w, acc[3]);
                acc[4]  = fmaf(s, w1.x, acc[4]);
                acc[5]  = fmaf(s, w1.y, acc[5]);
                acc[6]  = fmaf(s, w1.z, acc[6]);
                acc[7]  = fmaf(s, w1.w, acc[7]);
                acc[8]  = fmaf(s, w2.x, acc[8]);
                acc[9]  = fmaf(s, w2.y, acc[9]);
                acc[10] = fmaf(s, w2.z, acc[10]);
                acc[11] = fmaf(s, w2.w, acc[11]);
                acc[12] = fmaf(s, w3.x, acc[12]);
                acc[13] = fmaf(s, w3.y, acc[13]);
                acc[14] = fmaf(s, w3.z, acc[14]);
                acc[15] = fmaf(s, w3.w, acc[15]);
            }
        }
    }
    #pragma unroll
    for (int t = 0; t < 16; ++t) {
        acc[t] += dpp_f<QX1>(acc[t]);
        acc[t] += dpp_f<QX2>(acc[t]);
    }
    if (v < Vq) {
        float4 bv = *reinterpret_cast<const float4*>(bias + q * 4);
        float4 o = make_float4(acc[q * 4] + bv.x, acc[q * 4 + 1] + bv.y,
                               acc[q * 4 + 2] + bv.z, acc[q * 4 + 3] + bv.w);
        *reinterpret_cast<float4*>(table + (size_t)v * Tq + q * 4) = o;
    }
}

// ---------- gather: 15 one-level row_ror, or bpermute fallback ----------
#define G16_ROR(PV) \
      float r1 = ror_f<1>(PV),  r2 = ror_f<2>(PV),  r3 = ror_f<3>(PV); \
      float r4 = ror_f<4>(PV),  r5 = ror_f<5>(PV),  r6 = ror_f<6>(PV); \
      float r7 = ror_f<7>(PV),  r8v = ror_f<8>(PV), r9 = ror_f<9>(PV); \
      float r10 = ror_f<10>(PV), r11 = ror_f<11>(PV), r12v = ror_f<12>(PV); \
      float r13 = ror_f<13>(PV), r14 = ror_f<14>(PV), r15 = ror_f<15>(PV);

#define G16_BP(PV) \
      const int rb_ = (lane & 48) << 2; \
      float r1 = bperm_f(PV, rb_ + (pm[1] << 2)),  r2 = bperm_f(PV, rb_ + (pm[2] << 2)); \
      float r3 = bperm_f(PV, rb_ + (pm[3] << 2)),  r4 = bperm_f(PV, rb_ + (pm[4] << 2)); \
      float r5 = bperm_f(PV, rb_ + (pm[5] << 2)),  r6 = bperm_f(PV, rb_ + (pm[6] << 2)); \
      float r7 = bperm_f(PV, rb_ + (pm[7] << 2)),  r8v = bperm_f(PV, rb_ + (pm[8] << 2)); \
      float r9 = bperm_f(PV, rb_ + (pm[9] << 2)),  r10 = bperm_f(PV, rb_ + (pm[10] << 2)); \
      float r11 = bperm_f(PV, rb_ + (pm[11] << 2)), r12v = bperm_f(PV, rb_ + (pm[12] << 2)); \
      float r13 = bperm_f(PV, rb_ + (pm[13] << 2)), r14 = bperm_f(PV, rb_ + (pm[14] << 2)); \
      float r15 = bperm_f(PV, rb_ + (pm[15] << 2));

#define DEN_BODY(ff) \
      float a0 = P * Wt[0];     a0 = fmaf(r1, Wt[1], a0);   a0 = fmaf(r2, Wt[2], a0);   a0 = fmaf(r3, Wt[3], a0); \
      float a1 = r4 * Wt[4];    a1 = fmaf(r5, Wt[5], a1);   a1 = fmaf(r6, Wt[6], a1);   a1 = fmaf(r7, Wt[7], a1); \
      float a2 = r8v * Wt[8];   a2 = fmaf(r9, Wt[9], a2);   a2 = fmaf(r10, Wt[10], a2); a2 = fmaf(r11, Wt[11], a2); \
      float a3 = r12v * Wt[12]; a3 = fmaf(r13, Wt[13], a3); a3 = fmaf(r14, Wt[14], a3); a3 = fmaf(r15, Wt[15], a3); \
      P = ((a0 + a1) + (a2 + a3)) * (ff);

#define DSTEP_F(ff) { G16_ROR(P); DEN_BODY(ff) }
#define DSTEP_B(ff) { G16_BP(P);  DEN_BODY(ff) }

// vit step: P' = max_s(r_s + Wt[s]) + em (max3-shaped tree, no argmax, no store)
#define VIT_BODY(emv) \
      float v0 = P + Wt[0],     v1 = r1 + Wt[1],    v2 = r2 + Wt[2],    v3 = r3 + Wt[3]; \
      float v4 = r4 + Wt[4],    v5 = r5 + Wt[5],    v6 = r6 + Wt[6],    v7 = r7 + Wt[7]; \
      float v8 = r8v + Wt[8],   v9 = r9 + Wt[9],    v10 = r10 + Wt[10], v11 = r11 + Wt[11]; \
      float v12 = r12v + Wt[12], v13 = r13 + Wt[13], v14 = r14 + Wt[14], v15 = r15 + Wt[15]; \
      float m0 = fmaxf(fmaxf(v0, v1), v2),   m1 = fmaxf(fmaxf(v3, v4), v5); \
      float m2 = fmaxf(fmaxf(v6, v7), v8),   m3 = fmaxf(fmaxf(v9, v10), v11); \
      float m4 = fmaxf(fmaxf(v12, v13), v14); \
      float mA = fmaxf(fmaxf(m0, m1), m2),   mB = fmaxf(fmaxf(m3, m4), v15); \
      P = fmaxf(mA, mB) + (emv);

#define VSTEP_F(emv) { G16_ROR(P); VIT_BODY(emv) }
#define VSTEP_B(emv) { G16_BP(P);  VIT_BODY(emv) }

// branch-free group store: row b4 stores step t0+b4
#define VGSTORE(t0) { \
      float s01 = (b4 & 1) ? S1 : S0; \
      float s23 = (b4 & 1) ? S3 : S2; \
      scb[((t0) + b4) * Tq + j] = (b4 & 2) ? s23 : s01; }

// ---------- K1: CRF scans. grid=96, block=64 (1 wave). ----------
// blocks 0..31: den, 2 batches each. blocks 32..95: vit, 1 batch each.
__global__ __launch_bounds__(64) void k_scan(const int* __restrict__ src,
                                             const int* __restrict__ label,
                                             const int* __restrict__ pmask,
                                             const float* __restrict__ table,
                                             const float* __restrict__ start_t,
                                             const float* __restrict__ end_t,
                                             const float* __restrict__ trans,
                                             float* __restrict__ out) {
    __shared__ __align__(16) char smem[78848];

    const int lane = threadIdx.x;
    const int j  = lane & 15;          // state
    const int b4 = lane >> 4;          // row
    const bool vit = blockIdx.x >= 32;

    // ---- probe the ror network: decode slot -> state map pm[] ----
    int pm[16];
    bool fast;
    {
        float x = __int_as_float(j);
        G16_ROR(x);
        pm[0] = j;
        pm[1] = __float_as_int(r1);   pm[2] = __float_as_int(r2);   pm[3] = __float_as_int(r3);
        pm[4] = __float_as_int(r4);   pm[5] = __float_as_int(r5);   pm[6] = __float_as_int(r6);
        pm[7] = __float_as_int(r7);   pm[8] = __float_as_int(r8v);  pm[9] = __float_as_int(r9);
        pm[10] = __float_as_int(r10); pm[11] = __float_as_int(r11); pm[12] = __float_as_int(r12v);
        pm[13] = __float_as_int(r13); pm[14] = __float_as_int(r14); pm[15] = __float_as_int(r15);
        u32 cov = 0;
        bool inr = true;
        #pragma unroll
        for (int s = 0; s < 16; ++s) {
            inr = inr && (pm[s] >= 0) && (pm[s] < 16);
            cov |= 1u << (pm[s] & 15);
        }
        fast = (__all((inr && cov == 0xFFFFu) ? 1 : 0) != 0);
        if (!fast) {
            pm[0] = j;
            #pragma unroll
            for (int s = 1; s < 16; ++s) pm[s] = (j + s) & 15;
        }
    }

    if (!vit) {
        // ====================== DENOMINATOR (2 batches/wave) ======================
        float* emT = (float*)smem;                    // [2*16][EMP] FF values
        int* srcl  = (int*)(smem + 66048);            // [2][512]
        int* labl  = (int*)(smem + 70144);            // [2][512]
        const int bb = blockIdx.x * 2;
        const int bm = b4 & 1;
        const int batch = bb + bm;

        #pragma unroll
        for (int k = 0; k < 16; ++k) {
            int idx = lane + (k << 6);
            int bch = idx >> 9, t = idx & 511;
            srcl[idx] = src[(bb + bch) * Sq + t];
            labl[idx] = label[(bb + bch) * Sq + t];
        }
        __syncthreads();
        #pragma unroll 4
        for (int k = 0; k < 256; ++k) {
            int idx = lane + (k << 6);
            int bch = idx >> 13, rem = idx & 8191;
            int t = rem >> 4, jj = rem & 15;
            emT[(bch * 16 + jj) * EMP + t] =
                __expf(table[(size_t)srcl[(bch << 9) + t] * Tq + jj]) * 0.0625f;
        }
        __syncthreads();

        float Wt[16];
        #pragma unroll
        for (int s = 0; s < 16; ++s) Wt[s] = __expf(trans[pm[s] * Tq + j]);

        const float4* emrow = reinterpret_cast<const float4*>(emT + (bm * 16 + j) * EMP);
        float4 f0 = emrow[0];
        float P = __expf(start_t[j]) * f0.x * 16.0f;

        if (fast) {
            DSTEP_F(f0.y) DSTEP_F(f0.z) DSTEP_F(f0.w)
            float4 fc = emrow[1];
            #pragma unroll 2
            for (int g = 1; g < 128; ++g) {
                float4 fn = emrow[g + 1];          // g+1=128 reads pad, never consumed
                DSTEP_F(fc.x) DSTEP_F(fc.y) DSTEP_F(fc.z) DSTEP_F(fc.w)
                fc = fn;
            }
        } else {
            DSTEP_B(f0.y) DSTEP_B(f0.z) DSTEP_B(f0.w)
            float4 fc = emrow[1];
            #pragma unroll 2
            for (int g = 1; g < 128; ++g) {
                float4 fn = emrow[g + 1];
                DSTEP_B(fc.x) DSTEP_B(fc.y) DSTEP_B(fc.z) DSTEP_B(fc.w)
                fc = fn;
            }
        }
        float val = P * __expf(end_t[j]);
        val += dpp_f<QX1>(val); val += dpp_f<QX2>(val);
        val += dpp_f<RR4>(val); val += dpp_f<RR8>(val);
        float den = (float)(511.0 * 2.7725887222397811) + __logf(val);

        // numerator: 16 lanes per batch row
        float numv = 0.0f;
        int sl = 0;
        #pragma unroll
        for (int k = 0; k < 32; ++k) {
            int t = j + (k << 4);
            int tag = labl[(bm << 9) + t];
            int m = pmask[batch * Sq + t];
            sl += m;
            float emtt = table[(size_t)srcl[(bm << 9) + t] * Tq + tag];
            if (t == 0) {
                numv += start_t[tag] + emtt;
            } else {
                int tp = labl[(bm << 9) + t - 1];
                numv += (float)m * (trans[tp * Tq + tag] + emtt);
            }
        }
        numv += dpp_f<QX1>(numv); numv += dpp_f<QX2>(numv);
        numv += dpp_f<RR4>(numv); numv += dpp_f<RR8>(numv);
        sl += dpp_i<QX1>(sl); sl += dpp_i<QX2>(sl);
        sl += dpp_i<RR4>(sl); sl += dpp_i<RR8>(sl);
        if (j == 0 && b4 < 2) {
            int last = labl[(bm << 9) + sl - 1];
            float v = (numv + end_t[last]) - den;
            atomicAdd(out, -v * (1.0f / (float)Bq));
        }
    } else {
        // ====================== VITERBI (1 batch/wave) ======================
        float* em   = (float*)smem;                   // [16][EMP] raw logits
        float* scb  = (float*)(smem + 33024);         // [512][16] score trajectory
        u8*  hist   = (u8*)(smem + 65792);            // [512][16]
        int* srcl   = (int*)(smem + 73984);           // [512]
        int* labl   = (int*)(smem + 76032);           // [512]
        u8*  predi  = (u8*)(smem + 78080);            // [512]
        const int batch = blockIdx.x - 32;

        #pragma unroll
        for (int k = 0; k < 8; ++k) {
            int t = lane + (k << 6);
            srcl[t] = src[batch * Sq + t];
            labl[t] = label[batch * Sq + t];
        }
        __syncthreads();
        #pragma unroll 4
        for (int k = 0; k < 128; ++k) {
            int idx = lane + (k << 6);
            int t = idx >> 4, jj = idx & 15;
            em[jj * EMP + t] = table[(size_t)srcl[t] * Tq + jj];
        }
        __syncthreads();

        float Wt[16];
        #pragma unroll
        for (int s = 0; s < 16; ++s) Wt[s] = trans[pm[s] * Tq + j];

        const float4* emrow = reinterpret_cast<const float4*>(em + j * EMP);
        float4 f0 = emrow[0];
        float P = start_t[j] + f0.x;

        if (fast) {
            float S0 = P;
            VSTEP_F(f0.y) float S1 = P;
            VSTEP_F(f0.z) float S2 = P;
            VSTEP_F(f0.w) float S3 = P;
            VGSTORE(0)
            float4 fc = emrow[1];
            #pragma unroll 2
            for (int g = 1; g < 128; ++g) {
                float4 fn = emrow[g + 1];
                VSTEP_F(fc.x) S0 = P;
                VSTEP_F(fc.y) S1 = P;
                VSTEP_F(fc.z) S2 = P;
                VSTEP_F(fc.w) S3 = P;
                VGSTORE(g * 4)
                fc = fn;
            }
        } else {
            float S0 = P;
            VSTEP_B(f0.y) float S1 = P;
            VSTEP_B(f0.z) float S2 = P;
            VSTEP_B(f0.w) float S3 = P;
            VGSTORE(0)
            float4 fc = emrow[1];
            #pragma unroll 2
            for (int g = 1; g < 128; ++g) {
                float4 fn = emrow[g + 1];
                VSTEP_B(fc.x) S0 = P;
                VSTEP_B(fc.y) S1 = P;
                VSTEP_B(fc.z) S2 = P;
                VSTEP_B(fc.w) S3 = P;
                VGSTORE(g * 4)
                fc = fn;
            }
        }

        // final argmax within row (ties -> lowest state)
        float fv = P + end_t[j];
        int fi = j;
        #pragma unroll
        for (int off = 1; off < 16; off <<= 1) {
            float ov = __shfl_xor(fv, off);
            int oi = __shfl_xor(fi, off);
            bool take = (ov > fv) || (ov == fv && oi < fi);
            fv = take ? ov : fv;
            fi = take ? oi : fi;
        }
        __syncthreads();

        // ===== parallel post-pass: recompute hist rows (exact replay) =====
        {
            float Tt[16];
            #pragma unroll
            for (int m = 0; m < 16; ++m) Tt[m] = trans[m * Tq + j];
            const int r = b4;
            for (int k = 0; k < 128; ++k) {
                int t = 1 + r + 4 * k;
                if (t < Sq) {
                    const float4* sr = reinterpret_cast<const float4*>(scb + (t - 1) * Tq);
                    float4 s0 = sr[0], s1 = sr[1], s2 = sr[2], s3 = sr[3];
                    float w0 = s0.x + Tt[0],  w1 = s0.y + Tt[1],  w2 = s0.z + Tt[2],  w3 = s0.w + Tt[3];
                    float w4 = s1.x + Tt[4],  w5 = s1.y + Tt[5],  w6 = s1.z + Tt[6],  w7 = s1.w + Tt[7];
                    float w8 = s2.x + Tt[8],  w9 = s2.y + Tt[9],  wA = s2.z + Tt[10], wB = s2.w + Tt[11];
                    float wC = s3.x + Tt[12], wD = s3.y + Tt[13], wE = s3.z + Tt[14], wF = s3.w + Tt[15];
                    float ma = fmaxf(fmaxf(w0, w1), w2),  mb = fmaxf(fmaxf(w3, w4), w5);
                    float mc = fmaxf(fmaxf(w6, w7), w8),  md = fmaxf(fmaxf(w9, wA), wB);
                    float me = fmaxf(fmaxf(wC, wD), wE);
                    float mv = fmaxf(fmaxf(fmaxf(ma, mb), mc), fmaxf(fmaxf(md, me), wF));
                    // exact argmax: gap==0 -> y=i ; gap>=1 ulp -> y>=~1e24 >> 15
                    float y0 = fmaf(mv - w0, 1e30f, 0.0f),  y1 = fmaf(mv - w1, 1e30f, 1.0f);
                    float y2 = fmaf(mv - w2, 1e30f, 2.0f),  y3 = fmaf(mv - w3, 1e30f, 3.0f);
                    float y4 = fmaf(mv - w4, 1e30f, 4.0f),  y5 = fmaf(mv - w5, 1e30f, 5.0f);
                    float y6 = fmaf(mv - w6, 1e30f, 6.0f),  y7 = fmaf(mv - w7, 1e30f, 7.0f);
                    float y8 = fmaf(mv - w8, 1e30f, 8.0f),  y9 = fmaf(mv - w9, 1e30f, 9.0f);
                    float yA = fmaf(mv - wA, 1e30f, 10.0f), yB = fmaf(mv - wB, 1e30f, 11.0f);
                    float yC = fmaf(mv - wC, 1e30f, 12.0f), yD = fmaf(mv - wD, 1e30f, 13.0f);
                    float yE = fmaf(mv - wE, 1e30f, 14.0f), yF = fmaf(mv - wF, 1e30f, 15.0f);
                    float na = fminf(fminf(y0, y1), y2),  nb = fminf(fminf(y3, y4), y5);
                    float nc = fminf(fminf(y6, y7), y8),  nd2 = fminf(fminf(y9, yA), yB);
                    float ne = fminf(fminf(yC, yD), yE);
                    float ym = fminf(fminf(fminf(na, nb), nc), fminf(fminf(nd2, ne), yF));
                    hist[(t - 1) * Tq + j] = (unsigned char)(int)ym;
                }
            }
        }
        if (lane < 16) hist[511 * Tq + lane] = (u8)lane;  // identity row
        __syncthreads();

        // ===== backtrack via function-composition scan =====
        u64 rp[8];
        #pragma unroll
        for (int k = 0; k < 8; ++k) {
            uint4 rw = *reinterpret_cast<const uint4*>(&hist[(lane * 8 + k) * Tq]);
            u32 lo = packnib(rw.x) | (packnib(rw.y) << 16);
            u32 hi = packnib(rw.z) | (packnib(rw.w) << 16);
            rp[k] = (u64)lo | ((u64)hi << 32);
        }
        u64 F = rp[7];
        #pragma unroll
        for (int k = 6; k >= 0; --k) {
            u64 nf = 0;
            #pragma unroll
            for (int e = 0; e < 16; ++e) {
                u32 s = (u32)(F >> (e * 4)) & 15u;
                nf |= ((u64)nib64(rp[k], s)) << (e * 4);
            }
            F = nf;
        }
        u32 Flo = (u32)F, Fhi = (u32)(F >> 32);

        u32 pk[8] = {0, 0, 0, 0, 0, 0, 0, 0};
        u32 E = (u32)__builtin_amdgcn_readlane(fi, 0) & 15u;
        #pragma unroll 64
        for (int c = 63; c >= 0; --c) {
            u64 Fc = ((u64)(u32)__builtin_amdgcn_readlane((int)Fhi, c) << 32)
                   | (u64)(u32)__builtin_amdgcn_readlane((int)Flo, c);
            pk[c >> 3] |= E << ((c & 7) * 4);
            E = nib64(Fc, E);
        }

        u32 a0s = (lane & 8) ? pk[1] : pk[0];
        u32 a1s = (lane & 8) ? pk[3] : pk[2];
        u32 a2s = (lane & 8) ? pk[5] : pk[4];
        u32 a3s = (lane & 8) ? pk[7] : pk[6];
        u32 b0s = (lane & 16) ? a1s : a0s;
        u32 b1s = (lane & 16) ? a3s : a2s;
        u32 c0s = (lane & 32) ? b1s : b0s;
        u32 cur = (c0s >> ((lane & 7) * 4)) & 15u;
        u32 w0 = 0, w1 = 0;
        #pragma unroll
        for (int k = 7; k >= 0; --k) {
            cur = nib64(rp[k], cur);
            if (k >= 4) w1 |= cur << ((k - 4) * 8);
            else        w0 |= cur << (k * 8);
        }
        *reinterpret_cast<uint2*>(&predi[lane * 8]) = make_uint2(w0, w1);
        __syncthreads();

        // outputs
        int cnt = 0;
        #pragma unroll
        for (int k = 0; k < 8; ++k) {
            int s_ = lane + (k << 6);
            int lab = labl[s_];
            int pr = (int)predi[s_];
            int mpr = lab > 0 ? pr : 0;
            out[2 + batch * Sq + s_] = (float)mpr;
            out[2 + Bq * Sq + batch * Sq + s_] = (float)lab;
            cnt += (mpr == lab) ? 1 : 0;
        }
        #pragma unroll
        for (int off = 1; off < 64; off <<= 1) cnt += __shfl_xor(cnt, off);
        if (lane == 0) atomicAdd(out + 1, (float)cnt);
    }
}

extern "C" void kernel_launch(void* const* d_in, const int* in_sizes, int n_in,
                              void* d_out, int out_size, void* d_ws, size_t ws_size,
                              hipStream_t stream) {
    const int*   src   = (const int*)d_in[0];
    const int*   label = (const int*)d_in[1];
    const int*   pmask = (const int*)d_in[2];
    const float* emb   = (const float*)d_in[3];
    const float* W     = (const float*)d_in[4];
    const float* bias  = (const float*)d_in[5];
    const float* st    = (const float*)d_in[6];
    const float* en    = (const float*)d_in[7];
    const float* tr    = (const float*)d_in[8];
    float* out = (float*)d_out;

    float* table = (float*)d_ws;

    const int nblk = (Vq + 63) / 64;   // 477
    k_table<<<nblk, 256, 0, stream>>>(emb, W, bias, table, out);
    k_scan<<<96, 64, 0, stream>>>(src, label, pmask, table, st, en, tr, out);
}